// Round 10
// baseline (907.919 us; speedup 1.0000x reference)
//
#include <hip/hip_runtime.h>
#include <math.h>

typedef _Float16 f16;
typedef _Float16 f16x2 __attribute__((ext_vector_type(2)));
typedef _Float16 f16x4 __attribute__((ext_vector_type(4)));
typedef _Float16 f16x8 __attribute__((ext_vector_type(8)));
typedef float    f32x4 __attribute__((ext_vector_type(4)));

#define PKRTZ(a, b) __builtin_bit_cast(f16x2, __builtin_amdgcn_cvt_pkrtz((a), (b)))

#define NN 8192
#define DD 64
#define KT 32
#define NQB 64                 // queries per block (R6's proven shape)
#define NWAVES 4
#define KSPLIT 2               // key halves across blocks
#define KPW (NN / KSPLIT / NWAVES)   // 1024 keys per wave
#define NTILES (KPW / KT)            // 32

#define LOG2E 1.44269504088896f

// ---------------- kernel A: f32 -> f16 natural (Xn) + 32-key-tiled transpose (Xv) ----
#define LT_PITCH 66
__global__ __launch_bounds__(256, 2)
void prep_f16(const float* __restrict__ X, f16* __restrict__ Xn, f16* __restrict__ Xv)
{
  __shared__ f16 Lt[64 * LT_PITCH];
  const int tid  = threadIdx.x;
  const int b    = blockIdx.x >> 7;
  const int kb64 = (blockIdx.x & 127) * 64;

  {
    const int r = tid >> 2;
    const int c = (tid & 3) * 16;
    const float* p = X + ((size_t)(b * NN + kb64 + r)) * DD + c;
    const float4 a0 = *(const float4*)(p);
    const float4 a1 = *(const float4*)(p + 4);
    const float4 a2 = *(const float4*)(p + 8);
    const float4 a3 = *(const float4*)(p + 12);
    f16x8 v0, v1;
    v0[0]=(f16)a0.x; v0[1]=(f16)a0.y; v0[2]=(f16)a0.z; v0[3]=(f16)a0.w;
    v0[4]=(f16)a1.x; v0[5]=(f16)a1.y; v0[6]=(f16)a1.z; v0[7]=(f16)a1.w;
    v1[0]=(f16)a2.x; v1[1]=(f16)a2.y; v1[2]=(f16)a2.z; v1[3]=(f16)a2.w;
    v1[4]=(f16)a3.x; v1[5]=(f16)a3.y; v1[6]=(f16)a3.z; v1[7]=(f16)a3.w;
    f16* dn = Xn + ((size_t)(b * NN + kb64 + r)) * DD + c;
    *(f16x8*)(dn)     = v0;
    *(f16x8*)(dn + 8) = v1;
    *(f16x8*)&Lt[r * LT_PITCH + c]     = v0;
    *(f16x8*)&Lt[r * LT_PITCH + c + 8] = v1;
  }
  __syncthreads();
  {
    const int h    = tid >> 7;
    const int rem  = tid & 127;
    const int d    = rem >> 1;
    const int half = rem & 1;
    union { f16 s[16]; f16x8 v[2]; } u;
    #pragma unroll
    for (int j = 0; j < 16; ++j)
      u.s[j] = Lt[(h * 32 + half * 16 + j) * LT_PITCH + d];
    const int kt = (kb64 >> 5) + h;
    f16* dst = Xv + (((size_t)(b * (NN / 32) + kt)) * DD + d) * 32 + half * 16;
    *(f16x8*)&dst[0] = u.v[0];
    *(f16x8*)&dst[8] = u.v[1];
  }
}

// ---------------- kernel B: half-key attention, atomic merge into out ----------------
#define P_PITCH 36                        // f16; <=2-way banks
#define P_BYTES (NQB * P_PITCH * 2)       // 4608/wave; 4 waves = 18432
#define HL_PITCH 66                       // f32 pitch (2-way atomic banks)
#define WL_OFF   (64 * HL_PITCH * 4)      // 16896
#define SMEM_B   (2 * 64 * HL_PITCH * 4)  // 33792 -> 4 blocks/CU (135 KB LDS)

// (256,4): VGPR cap 128 under BOTH candidate launch_bounds semantics
// (min-blocks: 512/(4 blk x 1 w/SIMD); waves-per-EU: 512/4). R6 fit 112.
__global__ __launch_bounds__(256, 4)
void gconv_attn(const float* __restrict__ X, const f16* __restrict__ Xn,
                const f16* __restrict__ Xv, const float* __restrict__ W,
                float* __restrict__ out, float* __restrict__ Lws)
{
  __shared__ __align__(16) unsigned char smem[SMEM_B];

  const int tid  = threadIdx.x;
  const int lane = tid & 63;
  const int wave = tid >> 6;
  const int q15  = lane & 15;
  const int quad = lane >> 4;

  // batch = blockIdx&3: each XCD (round-robin mod 8) sees ONE batch -> 2 MB in its L2
  const int batch = blockIdx.x & 3;
  const int ks    = (blockIdx.x >> 2) & 1;         // key half
  const int qbase = (blockIdx.x >> 3) * NQB;
  const float* Xb = X + (size_t)batch * NN * DD;

  f16* Pw = (f16*)(smem + wave * P_BYTES);

  const int kstart = ks * (NN / KSPLIT) + wave * KPW;
  const f16* XnW = Xn + ((size_t)batch * NN + kstart) * DD + q15 * DD + quad * 8;
  const f16* XvW = Xv + ((size_t)batch * (NN / 32) + (kstart >> 5)) * DD * 32
                      + q15 * 32 + quad * 8;

  // ---- Q fragments (B-operand), exp2 domain; static max m2 (deterministic ->
  // identical across both ks blocks, so partials merge by plain addition) ----
  f16x8 qf[4][2];
  float m2[4], lrow[4];
  #pragma unroll
  for (int qt = 0; qt < 4; ++qt) {
    const float* qp = Xb + (size_t)(qbase + qt*16 + q15) * DD + quad*8;
    float nrm = 0.f;
    #pragma unroll
    for (int c = 0; c < 2; ++c) {
      const float4 a = *(const float4*)(qp + c*32);
      const float4 b = *(const float4*)(qp + c*32 + 4);
      float xs[8] = {a.x, a.y, a.z, a.w, b.x, b.y, b.z, b.w};
      f16x8 v;
      #pragma unroll
      for (int e = 0; e < 8; ++e) {
        const f16 ks2 = (f16)xs[e];
        const f16 qs  = (f16)(xs[e] * LOG2E);
        nrm += (float)qs * (float)ks2;
        v[e] = qs;
      }
      qf[qt][c] = v;
    }
    nrm += __shfl_xor(nrm, 16);
    nrm += __shfl_xor(nrm, 32);
    m2[qt] = nrm + 2.0f;
    lrow[qt] = 0.f;
  }

  f32x4 acc[4][4];
  #pragma unroll
  for (int a = 0; a < 4; ++a)
    #pragma unroll
    for (int b = 0; b < 4; ++b)
      acc[a][b] = (f32x4){0.f, 0.f, 0.f, 0.f};

  f16x8 kaA[2][2], kaB[2][2];

  auto load_ka = [&](f16x8 (&ka)[2][2], int t) {
    const f16* kn = XnW + (size_t)t * (KT * DD);
    #pragma unroll
    for (int g = 0; g < 2; ++g)
      #pragma unroll
      for (int c = 0; c < 2; ++c)
        ka[g][c] = *(const f16x8*)(kn + g * 16 * DD + c * 32);
  };

  auto process = [&](const f16x8 (&ka)[2][2], int t) {
    const f16* vn = XvW + (size_t)t * (DD * 32);
    f16x8 vb[4];
    #pragma unroll
    for (int mt = 0; mt < 4; ++mt)
      vb[mt] = *(const f16x8*)(vn + mt * 16 * 32);

    #pragma unroll
    for (int qt = 0; qt < 4; ++qt) {
      #pragma unroll
      for (int g = 0; g < 2; ++g) {
        f32x4 s = (f32x4){0.f, 0.f, 0.f, 0.f};
        s = __builtin_amdgcn_mfma_f32_16x16x32_f16(ka[g][0], qf[qt][0], s, 0, 0, 0);
        s = __builtin_amdgcn_mfma_f32_16x16x32_f16(ka[g][1], qf[qt][1], s, 0, 0, 0);
        const float p0 = __builtin_amdgcn_exp2f(s[0] - m2[qt]);
        const float p1 = __builtin_amdgcn_exp2f(s[1] - m2[qt]);
        const float p2 = __builtin_amdgcn_exp2f(s[2] - m2[qt]);
        const float p3 = __builtin_amdgcn_exp2f(s[3] - m2[qt]);
        lrow[qt] += (p0 + p1) + (p2 + p3);
        union { f16x4 v; f16x2 h[2]; } pu;
        pu.h[0] = PKRTZ(p0, p1);
        pu.h[1] = PKRTZ(p2, p3);
        *(f16x4*)&Pw[(qt*16 + q15)*P_PITCH + g*16 + quad*4] = pu.v;
      }
    }
    #pragma unroll
    for (int qt = 0; qt < 4; ++qt) {
      union { f16x8 v; f16x4 h[2]; } pu;
      pu.h[0] = *(const f16x4*)&Pw[(qt*16 + q15)*P_PITCH + quad*8];
      pu.h[1] = *(const f16x4*)&Pw[(qt*16 + q15)*P_PITCH + quad*8 + 4];
      #pragma unroll
      for (int mt = 0; mt < 4; ++mt)
        acc[qt][mt] = __builtin_amdgcn_mfma_f32_16x16x32_f16(vb[mt], pu.v, acc[qt][mt], 0, 0, 0);
    }
  };

  load_ka(kaA, 0);
  for (int t = 0; t < NTILES; t += 2) {
    load_ka(kaB, t + 1 < NTILES ? t + 1 : t);
    process(kaA, t);
    load_ka(kaA, t + 2 < NTILES ? t + 2 : t);
    process(kaB, t + 1 < NTILES ? t + 1 : t);
  }

  // ========= merge 4 waves' partials in LDS; l goes straight to global =========
  __syncthreads();
  float* Hl = (float*)smem;                  // [d=64][q=64] pitch 66
  float* Wl = (float*)(smem + WL_OFF);       // [d=64][o=64] pitch 66

  for (int i = tid; i < 64*HL_PITCH; i += 256) Hl[i] = 0.f;
  for (int i = tid; i < 64*64; i += 256) Wl[(i >> 6)*HL_PITCH + (i & 63)] = W[i];
  __syncthreads();

  float* Lrow = Lws + (size_t)batch * NN + qbase;
  #pragma unroll
  for (int qt = 0; qt < 4; ++qt) {
    float lr = lrow[qt];
    lr += __shfl_xor(lr, 16);
    lr += __shfl_xor(lr, 32);
    if (wave == 0 && quad == 0) atomicAdd(&Lrow[qt*16 + q15], lr);
    else if (wave != 0 && quad == 1 && wave == (tid >> 6)) { /* only wave0 adds per-block sum below */ }
    #pragma unroll
    for (int mt = 0; mt < 4; ++mt)
      #pragma unroll
      for (int rr = 0; rr < 4; ++rr)
        atomicAdd(&Hl[(mt*16 + quad*4 + rr)*HL_PITCH + qt*16 + q15], acc[qt][mt][rr]);
  }
  // NOTE: lrow was per-wave partial; wave0's lr above only covered wave0's keys.
  // Add the other waves' contributions too (distinct lanes -> one atomic each).
  #pragma unroll
  for (int qt = 0; qt < 4; ++qt) {
    if (wave != 0) {
      float lr = lrow[qt];
      lr += __shfl_xor(lr, 16);
      lr += __shfl_xor(lr, 32);
      if (quad == 0) atomicAdd(&Lrow[qt*16 + q15], lr);
    }
  }
  __syncthreads();

  // ========= partial projection (UNNORMALIZED): atomicAdd H.W into out =========
  {
    const int qq = tid >> 2;          // 64 queries, 4 threads each
    const int og = (tid & 3) * 16;    // 16 outputs per thread
    f32x4 o[4];
    #pragma unroll
    for (int i = 0; i < 4; ++i) o[i] = (f32x4){0.f,0.f,0.f,0.f};
    for (int d = 0; d < 64; ++d) {
      const float h = Hl[d*HL_PITCH + qq];
      const f32x4* wr = (const f32x4*)&Wl[d*HL_PITCH + og];
      #pragma unroll
      for (int i = 0; i < 4; ++i) o[i] += h * wr[i];
    }
    float* op = out + ((size_t)batch * NN + qbase + qq) * DD + og;
    #pragma unroll
    for (int i = 0; i < 4; ++i)
      #pragma unroll
      for (int e = 0; e < 4; ++e)
        atomicAdd(op + i*4 + e, o[i][e]);
  }
}

// ---------------- kernel C: out /= l ----------------
__global__ __launch_bounds__(256)
void divide_l(float* __restrict__ out, const float* __restrict__ Lws)
{
  const int i = blockIdx.x * 256 + threadIdx.x;   // f32x4 index, 524288 total
  f32x4 v = ((const f32x4*)out)[i];
  const float inv = 1.0f / Lws[i >> 4];           // 16 vec4 per row of 64
  ((f32x4*)out)[i] = v * inv;
}

extern "C" void kernel_launch(void* const* d_in, const int* in_sizes, int n_in,
                              void* d_out, int out_size, void* d_ws, size_t ws_size,
                              hipStream_t stream) {
  const float* X = (const float*)d_in[0];   // [4, 8192, 64] fp32
  const float* W = (const float*)d_in[1];   // [64, 64] fp32
  float* out = (float*)d_out;               // [4, 8192, 64] fp32

  f16*  Xn  = (f16*)d_ws;                                     // 4 MiB
  f16*  Xv  = (f16*)((char*)d_ws + (size_t)4 * NN * DD * 2);  // 4 MiB
  float* Lws = (float*)((char*)d_ws + (size_t)8 * NN * DD * 2); // 128 KiB

  hipMemsetAsync(out, 0, (size_t)4 * NN * DD * sizeof(float), stream);
  hipMemsetAsync(Lws, 0, (size_t)4 * NN * sizeof(float), stream);
  prep_f16 <<<dim3(512),  dim3(256), 0, stream>>>(X, Xn, Xv);
  gconv_attn<<<dim3(1024), dim3(256), 0, stream>>>(X, Xn, Xv, W, out, Lws);
  divide_l <<<dim3(2048), dim3(256), 0, stream>>>(out, Lws);
}

// Round 11
// 444.647 us; speedup vs baseline: 2.0419x; 2.0419x over previous
//
#include <hip/hip_runtime.h>
#include <math.h>

typedef _Float16 f16;
typedef _Float16 f16x2 __attribute__((ext_vector_type(2)));
typedef _Float16 f16x4 __attribute__((ext_vector_type(4)));
typedef _Float16 f16x8 __attribute__((ext_vector_type(8)));
typedef float    f32x4 __attribute__((ext_vector_type(4)));

#define PKRTZ(a, b) __builtin_bit_cast(f16x2, __builtin_amdgcn_cvt_pkrtz((a), (b)))

#define NN 8192
#define DD 64
#define KT 32
#define NQB 64                 // queries per block (R6's proven shape)
#define NWAVES 4
#define KSPLIT 2               // key halves split across blocks
#define KPW (NN / KSPLIT / NWAVES)   // 1024 keys per wave
#define NTILES (KPW / KT)            // 32

#define LOG2E 1.44269504088896f

// ---------------- kernel A: f32 -> f16 natural (Xn) + 32-key-tiled transpose (Xv) ----
#define LT_PITCH 66
__global__ __launch_bounds__(256, 2)
void prep_f16(const float* __restrict__ X, f16* __restrict__ Xn, f16* __restrict__ Xv)
{
  __shared__ f16 Lt[64 * LT_PITCH];
  const int tid  = threadIdx.x;
  const int b    = blockIdx.x >> 7;
  const int kb64 = (blockIdx.x & 127) * 64;

  {
    const int r = tid >> 2;
    const int c = (tid & 3) * 16;
    const float* p = X + ((size_t)(b * NN + kb64 + r)) * DD + c;
    const float4 a0 = *(const float4*)(p);
    const float4 a1 = *(const float4*)(p + 4);
    const float4 a2 = *(const float4*)(p + 8);
    const float4 a3 = *(const float4*)(p + 12);
    f16x8 v0, v1;
    v0[0]=(f16)a0.x; v0[1]=(f16)a0.y; v0[2]=(f16)a0.z; v0[3]=(f16)a0.w;
    v0[4]=(f16)a1.x; v0[5]=(f16)a1.y; v0[6]=(f16)a1.z; v0[7]=(f16)a1.w;
    v1[0]=(f16)a2.x; v1[1]=(f16)a2.y; v1[2]=(f16)a2.z; v1[3]=(f16)a2.w;
    v1[4]=(f16)a3.x; v1[5]=(f16)a3.y; v1[6]=(f16)a3.z; v1[7]=(f16)a3.w;
    f16* dn = Xn + ((size_t)(b * NN + kb64 + r)) * DD + c;
    *(f16x8*)(dn)     = v0;
    *(f16x8*)(dn + 8) = v1;
    *(f16x8*)&Lt[r * LT_PITCH + c]     = v0;
    *(f16x8*)&Lt[r * LT_PITCH + c + 8] = v1;
  }
  __syncthreads();
  {
    const int h    = tid >> 7;
    const int rem  = tid & 127;
    const int d    = rem >> 1;
    const int half = rem & 1;
    union { f16 s[16]; f16x8 v[2]; } u;
    #pragma unroll
    for (int j = 0; j < 16; ++j)
      u.s[j] = Lt[(h * 32 + half * 16 + j) * LT_PITCH + d];
    const int kt = (kb64 >> 5) + h;
    f16* dst = Xv + (((size_t)(b * (NN / 32) + kt)) * DD + d) * 32 + half * 16;
    *(f16x8*)&dst[0] = u.v[0];
    *(f16x8*)&dst[8] = u.v[1];
  }
}

// ---------------- kernel B: half-key attention, atomic merge into out ----------------
#define P_PITCH 36                        // f16; <=2-way banks
#define P_BYTES (NQB * P_PITCH * 2)       // 4608/wave; 4 waves = 18432
#define HL_PITCH 66                       // f32 pitch
#define WL_OFF   (64 * HL_PITCH * 4)      // 16896
#define SMEM_B   (2 * 64 * HL_PITCH * 4)  // 33792 -> 4 blocks/CU (135 KB LDS)

// LAUNCH-BOUNDS LAW (measured R1-R10): VGPR cap = 256/arg2, independent of
// block size. arg2=4 -> 64-reg cap -> catastrophic spill for this ~112-reg
// kernel (R4/R7/R8/R10). arg2=2 -> 128-reg cap: fits (R6: 112, no spill).
// 4 waves/SIMD comes from grid (1024 blocks = 4 blocks/CU) + hw limits
// (4 x 112 = 448 <= 512 VGPR/SIMD; 4 x 33.8 KB = 135 <= 160 KB LDS).
__global__ __launch_bounds__(256, 2)
void gconv_attn(const float* __restrict__ X, const f16* __restrict__ Xn,
                const f16* __restrict__ Xv, const float* __restrict__ W,
                float* __restrict__ out, float* __restrict__ Lws)
{
  __shared__ __align__(16) unsigned char smem[SMEM_B];

  const int tid  = threadIdx.x;
  const int lane = tid & 63;
  const int wave = tid >> 6;
  const int q15  = lane & 15;
  const int quad = lane >> 4;

  // batch = blockIdx&3: each XCD (round-robin mod 8) sees ONE batch -> 2 MB in its L2
  const int batch = blockIdx.x & 3;
  const int ks    = (blockIdx.x >> 2) & 1;         // key half
  const int qbase = (blockIdx.x >> 3) * NQB;
  const float* Xb = X + (size_t)batch * NN * DD;

  f16* Pw = (f16*)(smem + wave * P_BYTES);

  const int kstart = ks * (NN / KSPLIT) + wave * KPW;
  const f16* XnW = Xn + ((size_t)batch * NN + kstart) * DD + q15 * DD + quad * 8;
  const f16* XvW = Xv + ((size_t)batch * (NN / 32) + (kstart >> 5)) * DD * 32
                      + q15 * 32 + quad * 8;

  // ---- Q fragments (B-operand), exp2 domain; static max m2 (deterministic ->
  // identical across both ks blocks, so partials merge by plain addition) ----
  f16x8 qf[4][2];
  float m2[4], lrow[4];
  #pragma unroll
  for (int qt = 0; qt < 4; ++qt) {
    const float* qp = Xb + (size_t)(qbase + qt*16 + q15) * DD + quad*8;
    float nrm = 0.f;
    #pragma unroll
    for (int c = 0; c < 2; ++c) {
      const float4 a = *(const float4*)(qp + c*32);
      const float4 b = *(const float4*)(qp + c*32 + 4);
      float xs[8] = {a.x, a.y, a.z, a.w, b.x, b.y, b.z, b.w};
      f16x8 v;
      #pragma unroll
      for (int e = 0; e < 8; ++e) {
        const f16 kc = (f16)xs[e];
        const f16 qs = (f16)(xs[e] * LOG2E);
        nrm += (float)qs * (float)kc;
        v[e] = qs;
      }
      qf[qt][c] = v;
    }
    nrm += __shfl_xor(nrm, 16);
    nrm += __shfl_xor(nrm, 32);
    m2[qt] = nrm + 2.0f;
    lrow[qt] = 0.f;
  }

  f32x4 acc[4][4];
  #pragma unroll
  for (int a = 0; a < 4; ++a)
    #pragma unroll
    for (int b = 0; b < 4; ++b)
      acc[a][b] = (f32x4){0.f, 0.f, 0.f, 0.f};

  f16x8 kaA[2][2], kaB[2][2];

  auto load_ka = [&](f16x8 (&ka)[2][2], int t) {
    const f16* kn = XnW + (size_t)t * (KT * DD);
    #pragma unroll
    for (int g = 0; g < 2; ++g)
      #pragma unroll
      for (int c = 0; c < 2; ++c)
        ka[g][c] = *(const f16x8*)(kn + g * 16 * DD + c * 32);
  };

  auto process = [&](const f16x8 (&ka)[2][2], int t) {
    const f16* vn = XvW + (size_t)t * (DD * 32);
    f16x8 vb[4];
    #pragma unroll
    for (int mt = 0; mt < 4; ++mt)
      vb[mt] = *(const f16x8*)(vn + mt * 16 * 32);

    #pragma unroll
    for (int qt = 0; qt < 4; ++qt) {
      #pragma unroll
      for (int g = 0; g < 2; ++g) {
        f32x4 s = (f32x4){0.f, 0.f, 0.f, 0.f};
        s = __builtin_amdgcn_mfma_f32_16x16x32_f16(ka[g][0], qf[qt][0], s, 0, 0, 0);
        s = __builtin_amdgcn_mfma_f32_16x16x32_f16(ka[g][1], qf[qt][1], s, 0, 0, 0);
        const float p0 = __builtin_amdgcn_exp2f(s[0] - m2[qt]);
        const float p1 = __builtin_amdgcn_exp2f(s[1] - m2[qt]);
        const float p2 = __builtin_amdgcn_exp2f(s[2] - m2[qt]);
        const float p3 = __builtin_amdgcn_exp2f(s[3] - m2[qt]);
        lrow[qt] += (p0 + p1) + (p2 + p3);
        union { f16x4 v; f16x2 h[2]; } pu;
        pu.h[0] = PKRTZ(p0, p1);
        pu.h[1] = PKRTZ(p2, p3);
        *(f16x4*)&Pw[(qt*16 + q15)*P_PITCH + g*16 + quad*4] = pu.v;
      }
    }
    #pragma unroll
    for (int qt = 0; qt < 4; ++qt) {
      union { f16x8 v; f16x4 h[2]; } pu;
      pu.h[0] = *(const f16x4*)&Pw[(qt*16 + q15)*P_PITCH + quad*8];
      pu.h[1] = *(const f16x4*)&Pw[(qt*16 + q15)*P_PITCH + quad*8 + 4];
      #pragma unroll
      for (int mt = 0; mt < 4; ++mt)
        acc[qt][mt] = __builtin_amdgcn_mfma_f32_16x16x32_f16(vb[mt], pu.v, acc[qt][mt], 0, 0, 0);
    }
  };

  load_ka(kaA, 0);
  for (int t = 0; t < NTILES; t += 2) {
    load_ka(kaB, t + 1 < NTILES ? t + 1 : t);
    process(kaA, t);
    load_ka(kaA, t + 2 < NTILES ? t + 2 : t);
    process(kaB, t + 1 < NTILES ? t + 1 : t);
  }

  // ========= merge 4 waves' partials in LDS; l partials atomically to global =========
  __syncthreads();
  float* Hl = (float*)smem;                  // [d=64][q=64] pitch 66
  float* Wl = (float*)(smem + WL_OFF);       // [d=64][o=64] pitch 66

  for (int i = tid; i < 64*HL_PITCH; i += 256) Hl[i] = 0.f;
  for (int i = tid; i < 64*64; i += 256) Wl[(i >> 6)*HL_PITCH + (i & 63)] = W[i];
  __syncthreads();

  float* Lrow = Lws + (size_t)batch * NN + qbase;
  #pragma unroll
  for (int qt = 0; qt < 4; ++qt) {
    float lr = lrow[qt];
    lr += __shfl_xor(lr, 16);
    lr += __shfl_xor(lr, 32);
    if (quad == 0) atomicAdd(&Lrow[qt*16 + q15], lr);   // one atomic per (wave,q)
    #pragma unroll
    for (int mt = 0; mt < 4; ++mt)
      #pragma unroll
      for (int rr = 0; rr < 4; ++rr)
        atomicAdd(&Hl[(mt*16 + quad*4 + rr)*HL_PITCH + qt*16 + q15], acc[qt][mt][rr]);
  }
  __syncthreads();

  // ========= partial projection (UNNORMALIZED): atomicAdd H.W into out =========
  {
    const int qq = tid >> 2;          // 64 queries, 4 threads each
    const int og = (tid & 3) * 16;    // 16 outputs per thread
    f32x4 o[4];
    #pragma unroll
    for (int i = 0; i < 4; ++i) o[i] = (f32x4){0.f,0.f,0.f,0.f};
    for (int d = 0; d < 64; ++d) {
      const float h = Hl[d*HL_PITCH + qq];
      const f32x4* wr = (const f32x4*)&Wl[d*HL_PITCH + og];
      #pragma unroll
      for (int i = 0; i < 4; ++i) o[i] += h * wr[i];
    }
    float* op = out + ((size_t)batch * NN + qbase + qq) * DD + og;
    #pragma unroll
    for (int i = 0; i < 4; ++i)
      #pragma unroll
      for (int e = 0; e < 4; ++e)
        atomicAdd(op + i*4 + e, o[i][e]);
  }
}

// ---------------- kernel C: out /= l ----------------
__global__ __launch_bounds__(256)
void divide_l(float* __restrict__ out, const float* __restrict__ Lws)
{
  const int i = blockIdx.x * 256 + threadIdx.x;   // f32x4 index, 524288 total
  f32x4 v = ((const f32x4*)out)[i];
  const float inv = 1.0f / Lws[i >> 4];           // 16 vec4 per row of 64
  ((f32x4*)out)[i] = v * inv;
}

extern "C" void kernel_launch(void* const* d_in, const int* in_sizes, int n_in,
                              void* d_out, int out_size, void* d_ws, size_t ws_size,
                              hipStream_t stream) {
  const float* X = (const float*)d_in[0];   // [4, 8192, 64] fp32
  const float* W = (const float*)d_in[1];   // [64, 64] fp32
  float* out = (float*)d_out;               // [4, 8192, 64] fp32

  f16*  Xn  = (f16*)d_ws;                                       // 4 MiB
  f16*  Xv  = (f16*)((char*)d_ws + (size_t)4 * NN * DD * 2);    // 4 MiB
  float* Lws = (float*)((char*)d_ws + (size_t)8 * NN * DD * 2); // 128 KiB

  hipMemsetAsync(out, 0, (size_t)4 * NN * DD * sizeof(float), stream);
  hipMemsetAsync(Lws, 0, (size_t)4 * NN * sizeof(float), stream);
  prep_f16  <<<dim3(512),  dim3(256), 0, stream>>>(X, Xn, Xv);
  gconv_attn<<<dim3(1024), dim3(256), 0, stream>>>(X, Xn, Xv, W, out, Lws);
  divide_l  <<<dim3(2048), dim3(256), 0, stream>>>(out, Lws);
}